// Round 3
// baseline (697.240 us; speedup 1.0000x reference)
//
#include <hip/hip_runtime.h>

// SmallSNN: T=50, B=128, ni=16384, nh=256, no=11
// Pipeline: convert_w1 (one-time fp32 -> f16 hi/lo limb split of W1)
//        -> gemm1_mfma (f16x2-limb split-fp32 MFMA, split-K=8,
//                       XOR-swizzled LDS + global_load_lds B staging)
//        -> fused_tail (split-K reduce + mem1 recursion + gemm2 + mem2
//                       recursion in ONE kernel; spk1/cur2 stay on-chip)

#define T_STEPS 50
#define BATCH   128
#define NI      16384
#define NH      256
#define NO      11
#define M_TOT   (T_STEPS * BATCH)   // 6400
#define KSPLIT  8
#define KCHUNK  (NI / KSPLIT)       // 2048
#define BK      32
#define KTILES  (KCHUNK / BK)       // 64
#define BM      128
#define BN      256

typedef _Float16 f16x8 __attribute__((ext_vector_type(8)));
typedef _Float16 f16x4 __attribute__((ext_vector_type(4)));
typedef float    f32x4 __attribute__((ext_vector_type(4)));

__device__ __forceinline__ void split2(float f, _Float16& hi, _Float16& lo) {
    hi = (_Float16)f;                 // RN
    lo = (_Float16)(f - (float)hi);   // exact residual, then RN -> ~2^-24 total
}

// LDS tiles are [rows][BK=32] f16 (64B rows). Unswizzled fragment reads are an
// 8-way bank conflict. XOR the 16B-block index with ((row>>1)&3): per 16-lane
// phase both reads and writes cover all 32 banks 2 dwords deep -> conflict-free.
__device__ __forceinline__ int swz(int row, int blk) {
    return row * BK + ((blk ^ ((row >> 1) & 3)) << 3);
}

typedef __attribute__((address_space(1))) const unsigned int guint;
typedef __attribute__((address_space(3))) unsigned int luint;
__device__ __forceinline__ void lds16(const void* g, void* l) {
    // async 16B/lane global->LDS DMA; LDS dest = wave-uniform base + lane*16
    __builtin_amdgcn_global_load_lds((guint*)g, (luint*)l, 16, 0, 0);
}

// ---------------------------------------------------------------------------
// one-time W1 fp32 -> f16 hi/lo limbs (bitwise identical to per-tile split2)
// ---------------------------------------------------------------------------
__global__ __launch_bounds__(256) void convert_w1(
    const float* __restrict__ W1, _Float16* __restrict__ Wh, _Float16* __restrict__ Wl)
{
    const size_t i = ((size_t)blockIdx.x * 256 + threadIdx.x) * 4;
    const float4 v = *(const float4*)(W1 + i);
    float a[4] = { v.x, v.y, v.z, v.w };
    f16x4 h, l;
#pragma unroll
    for (int j = 0; j < 4; ++j) {
        _Float16 hh, ll;
        split2(a[j], hh, ll);
        h[j] = hh; l[j] = ll;
    }
    *(f16x4*)(Wh + i) = h;
    *(f16x4*)(Wl + i) = l;
}

// ---------------------------------------------------------------------------
// gemm1: part[ks][m][n] = sum_{k in chunk ks} X[m][k] * W1[n][k]
// 128x256 block tile, 4 waves of 64x128, 16x16x32 f16 MFMA, 3 limb products.
// ---------------------------------------------------------------------------
__global__ __launch_bounds__(256, 2) void gemm1_mfma(
    const float* __restrict__ X, const _Float16* __restrict__ W1h,
    const _Float16* __restrict__ W1l, float* __restrict__ part)
{
    __shared__ alignas(16) _Float16 Ah[BM * BK];   // 8 KB
    __shared__ alignas(16) _Float16 Al[BM * BK];   // 8 KB
    __shared__ alignas(16) _Float16 Bh[BN * BK];   // 16 KB
    __shared__ alignas(16) _Float16 Bl[BN * BK];   // 16 KB

    const int tid  = threadIdx.x;
    const int lane = tid & 63;
    const int wave = tid >> 6;
    const int wm   = wave >> 1;       // 0..1 : m offset 64*wm
    const int wn   = wave & 1;        // 0..1 : n offset 128*wn
    const int q    = lane >> 4;       // quad 0..3
    const int l15  = lane & 15;

    const int m0 = blockIdx.x * BM;   // 0..6272
    const int ks = blockIdx.y;        // 0..7
    const int kbase = ks * KCHUNK;

    const int a_row[2] = { tid >> 2, 64 + (tid >> 2) };
    const int a_g8     = tid & 3;

    // B DMA: lane i stores LDS slot (row = base+(i>>2), block = i&3); it must
    // FETCH global block (i&3) ^ ((row>>1)&3) so LDS holds the swizzled layout.
    int b_row[4], b_fb[4];
#pragma unroll
    for (int j = 0; j < 4; ++j) {
        b_row[j] = wave * 64 + j * 16 + (lane >> 2);
        b_fb[j]  = (lane & 3) ^ ((b_row[j] >> 1) & 3);
    }

    f32x4 acc[4][8];
#pragma unroll
    for (int im = 0; im < 4; ++im)
#pragma unroll
        for (int jn = 0; jn < 8; ++jn) acc[im][jn] = (f32x4){0.f, 0.f, 0.f, 0.f};

    // fragment-read swizzle: row = (16-mult) + l15 -> ((row>>1)&3) == ((l15>>1)&3)
    const int xsw = (l15 >> 1) & 3;
    const int qx  = (q ^ xsw) << 3;

    for (int kt = 0; kt < KTILES; ++kt) {
        const int k0 = kbase + kt * BK;

        // ---- A: global fp32 loads + limb conversion (regs, pre-barrier) ----
        f16x8 ahv[2], alv[2];
#pragma unroll
        for (int i = 0; i < 2; ++i) {
            const float* s = X + (size_t)(m0 + a_row[i]) * NI + k0 + a_g8 * 8;
            const float4 v0 = *(const float4*)s, v1 = *(const float4*)(s + 4);
            float av[8] = { v0.x, v0.y, v0.z, v0.w, v1.x, v1.y, v1.z, v1.w };
#pragma unroll
            for (int j = 0; j < 8; ++j) { _Float16 h, l; split2(av[j], h, l); ahv[i][j] = h; alv[i][j] = l; }
        }

        __syncthreads();   // all waves done reading previous tile

        // ---- B: async DMA into linear LDS (content pre-swizzled via source) ----
#pragma unroll
        for (int j = 0; j < 4; ++j) {
            const size_t goff = (size_t)b_row[j] * NI + k0 + b_fb[j] * 8;
            const int lbase = (wave * 4 + j) * 512;   // 16 rows * 32 f16
            lds16(W1h + goff, &Bh[lbase]);
            lds16(W1l + goff, &Bl[lbase]);
        }

        // ---- A: swizzled LDS stores ----
#pragma unroll
        for (int i = 0; i < 2; ++i) {
            const int off = swz(a_row[i], a_g8);
            *(f16x8*)&Ah[off] = ahv[i];
            *(f16x8*)&Al[off] = alv[i];
        }

        __syncthreads();   // staging + DMA visible

        // ---- fragments + MFMA ----
        f16x8 fah[4], fal[4];
#pragma unroll
        for (int im = 0; im < 4; ++im) {
            const int off = (64 * wm + 16 * im + l15) * BK + qx;
            fah[im] = *(const f16x8*)&Ah[off];
            fal[im] = *(const f16x8*)&Al[off];
        }
#pragma unroll
        for (int jn = 0; jn < 8; ++jn) {
            const int off = (128 * wn + 16 * jn + l15) * BK + qx;
            const f16x8 fbh = *(const f16x8*)&Bh[off];
            const f16x8 fbl = *(const f16x8*)&Bl[off];
#pragma unroll
            for (int im = 0; im < 4; ++im) {
                acc[im][jn] = __builtin_amdgcn_mfma_f32_16x16x32_f16(fah[im], fbh, acc[im][jn], 0, 0, 0);
                acc[im][jn] = __builtin_amdgcn_mfma_f32_16x16x32_f16(fal[im], fbh, acc[im][jn], 0, 0, 0);
                acc[im][jn] = __builtin_amdgcn_mfma_f32_16x16x32_f16(fah[im], fbl, acc[im][jn], 0, 0, 0);
            }
        }
    }

    // ---- epilogue: write fp32 partials ----
    float* P = part + (size_t)ks * M_TOT * NH;
#pragma unroll
    for (int im = 0; im < 4; ++im) {
        const int mrow = m0 + 64 * wm + 16 * im + 4 * q;
#pragma unroll
        for (int jn = 0; jn < 8; ++jn) {
            const int n = 128 * wn + 16 * jn + l15;
#pragma unroll
            for (int r = 0; r < 4; ++r)
                P[(size_t)(mrow + r) * NH + n] = acc[im][jn][r];
        }
    }
}

// ---------------------------------------------------------------------------
// fused tail: per batch-element block. Thread h runs the layer-1 membrane
// recursion (split-K reduce + bias); spk1 row lives in LDS only. 4 waves then
// compute the 11 layer-2 dot products (wave w owns o = w, w+4, w+8) with a
// shfl-xor tree identical to the old gemm2, and run the layer-2 recursion
// inline. Next timestep's partials are prefetched during the reduce phase.
// Reduction orders match the old scan1/gemm2/scan2 bitwise.
// ---------------------------------------------------------------------------
__global__ __launch_bounds__(256) void fused_tail(
    const float* __restrict__ part, const float* __restrict__ b1,
    const float* __restrict__ W2, const float* __restrict__ b2,
    float* __restrict__ out)
{
    __shared__ float sp[NH];           // spk1 row for this (t, b)
    __shared__ float w2s[NO * NH];     // 11.3 KB, staged once

    const int b    = blockIdx.x;       // 0..127
    const int h    = threadIdx.x;      // 0..255
    const int wave = h >> 6;
    const int lane = h & 63;

    // stage W2
    for (int i = h; i < NO * NH; i += 256) w2s[i] = W2[i];

    const float bias = b1[h];
    const size_t S = (size_t)M_TOT * NH;

    // per-wave layer-2 outputs: o = wave + 4*oi (skip o >= 11)
    float mem2[3] = {0.f, 0.f, 0.f};
    float bias2[3];
#pragma unroll
    for (int oi = 0; oi < 3; ++oi) {
        const int o = wave + 4 * oi;
        bias2[oi] = (o < NO) ? b2[o] : 0.f;
    }

    float mem1 = 0.f;
    float c8[8], cn8[8];

    // preload t=0 partials
    {
        const size_t idx = (size_t)b * NH + h;
#pragma unroll
        for (int ksi = 0; ksi < 8; ++ksi) c8[ksi] = part[ksi * S + idx];
    }

    __syncthreads();   // w2s staged

    for (int t = 0; t < T_STEPS; ++t) {
        // prefetch next timestep's partials (hidden under gemm2 phase)
        if (t + 1 < T_STEPS) {
            const size_t idx = ((size_t)((t + 1) * BATCH + b)) * NH + h;
#pragma unroll
            for (int ksi = 0; ksi < 8; ++ksi) cn8[ksi] = part[ksi * S + idx];
        }

        // ---- layer 1: split-K reduce (same parenthesization as scan1) ----
        float c = ((c8[0] + c8[1]) + (c8[2] + c8[3]))
                + ((c8[4] + c8[5]) + (c8[6] + c8[7]));
        c += bias;
        mem1 = __fadd_rn(__fmul_rn(0.9f, mem1), c);
        const float s1 = (mem1 > 1.0f) ? 1.0f : 0.0f;
        mem1 -= s1;
        sp[h] = s1;

        __syncthreads();   // spk1 row visible

        // ---- layer 2: 11 dot products + membrane recursion ----
        const float4 s4 = *(const float4*)&sp[lane << 2];
#pragma unroll
        for (int oi = 0; oi < 3; ++oi) {
            const int o = wave + 4 * oi;
            if (o < NO) {
                const float4 w4 = *(const float4*)&w2s[o * NH + (lane << 2)];
                float p = (s4.x * w4.x + s4.y * w4.y) + (s4.z * w4.z + s4.w * w4.w);
#pragma unroll
                for (int d = 32; d; d >>= 1) p += __shfl_xor(p, d, 64);
                const float c2 = p + bias2[oi];
                mem2[oi] = __fadd_rn(__fmul_rn(0.9f, mem2[oi]), c2);
                const float s2 = (mem2[oi] > 1.0f) ? 1.0f : 0.0f;
                mem2[oi] -= s2;
                if (lane == 0) out[(size_t)(t * BATCH + b) * NO + o] = s2;
            }
        }

        __syncthreads();   // protect sp before next t overwrites

#pragma unroll
        for (int ksi = 0; ksi < 8; ++ksi) c8[ksi] = cn8[ksi];
    }
}

extern "C" void kernel_launch(void* const* d_in, const int* in_sizes, int n_in,
                              void* d_out, int out_size, void* d_ws, size_t ws_size,
                              hipStream_t stream) {
    const float* x  = (const float*)d_in[0];   // [50,128,128,128]
    const float* W1 = (const float*)d_in[1];   // [256,16384]
    const float* b1 = (const float*)d_in[2];   // [256]
    const float* W2 = (const float*)d_in[3];   // [11,256]
    const float* b2 = (const float*)d_in[4];   // [11]
    float* out = (float*)d_out;                // [50,128,11]

    float* part = (float*)d_ws;                          // 8 * 6400*256 fp32 = 52.4 MB
    _Float16* W1h = (_Float16*)(part + (size_t)KSPLIT * M_TOT * NH);  // 8 MB
    _Float16* W1l = W1h + (size_t)NH * NI;                            // 8 MB

    convert_w1<<<(NH * NI) / (256 * 4), 256, 0, stream>>>(W1, W1h, W1l);
    dim3 g1(M_TOT / BM, KSPLIT);                         // (50, 8)
    gemm1_mfma<<<g1, 256, 0, stream>>>(x, W1h, W1l, part);
    fused_tail<<<BATCH, NH, 0, stream>>>(part, b1, W2, b2, out);
}